// Round 9
// baseline (275.213 us; speedup 1.0000x reference)
//
#include <hip/hip_runtime.h>
#include <float.h>

#define N_ROWS  32768
#define K_CODES 8192
#define DIM     64
#define KSPLIT  32
#define KPART   (K_CODES / KSPLIT)   // 256 codes per slab
#define QS      (KPART / 4)          // 64 codes per quarter-slab task
#define DELTA_D 2e-4f

typedef __attribute__((ext_vector_type(8))) short bf16x8;
typedef __attribute__((ext_vector_type(4))) float f32x4;

// ws layout (bytes):
#define WS_PARTIALS 0          // 2048 f    (8 KB)
#define WS_ZSQ      8192       // 32768 f   (128 KB)
#define WS_EBF      139264     // 8192*64 bf16 frag-order (1 MB)
#define WS_ZBF      1187840    // 32768*64 bf16 frag-order (4 MB)
#define WS_SLABROWS 1187840    // [32][32768] i (4 MB) — overlays ZBF (dead after sweep)
#define WS_MAX      5382144    // [32][32768] f (4 MB)
#define WS_SLABCNT  9576448    // 32 i (pad to 512 B)
#define WS_BEST     9576960    // 32768 u64 (256 KB) -> total ~9.84 MB

__device__ __forceinline__ unsigned short f2bf(float f) {
  unsigned u = __float_as_uint(f);
  u = (u + 0x7fffu + ((u >> 16) & 1u)) >> 16;   // RNE, finite inputs
  return (unsigned short)u;
}

__device__ __forceinline__ void gload_lds16(const void* g, void* l) {
  typedef const __attribute__((address_space(1))) unsigned int* gp_t;
  typedef __attribute__((address_space(3))) unsigned int* lp_t;
  __builtin_amdgcn_global_load_lds((gp_t)g, (lp_t)l, 16, 0, 0);
}

#define MFMA16(a, b, c) __builtin_amdgcn_mfma_f32_16x16x32_bf16((a), (b), (c), 0, 0, 0)

// ----------------------------------------------------------------- z_sq ----
// Bit-exact numpy pairwise sum of z*z over 64 elems (validated round 2).
__global__ __launch_bounds__(256) void vq_zsq(const float* __restrict__ z,
                                              float* __restrict__ zsq) {
  const int row = blockIdx.x * 256 + threadIdx.x;
  const float4* z4 = reinterpret_cast<const float4*>(z + (size_t)row * DIM);
  float r[8];
  {
    const float4 v0 = z4[0], v1 = z4[1];
    r[0] = __fmul_rn(v0.x, v0.x); r[1] = __fmul_rn(v0.y, v0.y);
    r[2] = __fmul_rn(v0.z, v0.z); r[3] = __fmul_rn(v0.w, v0.w);
    r[4] = __fmul_rn(v1.x, v1.x); r[5] = __fmul_rn(v1.y, v1.y);
    r[6] = __fmul_rn(v1.z, v1.z); r[7] = __fmul_rn(v1.w, v1.w);
  }
#pragma unroll
  for (int i = 1; i < 8; ++i) {
    const float4 v0 = z4[2 * i], v1 = z4[2 * i + 1];
    r[0] = __fadd_rn(r[0], __fmul_rn(v0.x, v0.x));
    r[1] = __fadd_rn(r[1], __fmul_rn(v0.y, v0.y));
    r[2] = __fadd_rn(r[2], __fmul_rn(v0.z, v0.z));
    r[3] = __fadd_rn(r[3], __fmul_rn(v0.w, v0.w));
    r[4] = __fadd_rn(r[4], __fmul_rn(v1.x, v1.x));
    r[5] = __fadd_rn(r[5], __fmul_rn(v1.y, v1.y));
    r[6] = __fadd_rn(r[6], __fmul_rn(v1.z, v1.z));
    r[7] = __fadd_rn(r[7], __fmul_rn(v1.w, v1.w));
  }
  zsq[row] = __fadd_rn(
      __fadd_rn(__fadd_rn(r[0], r[1]), __fadd_rn(r[2], r[3])),
      __fadd_rn(__fadd_rn(r[4], r[5]), __fadd_rn(r[6], r[7])));
}

// ------------------------------------------------- cvt to fragment order ----
// chunk c (8 bf16 = 16B): l=c&63, h=(c>>6)&1, t=c>>7
//   dst[c] = src[idx = t*16 + (l&15)][d = h*32 + (l>>4)*8 .. +8]
__global__ __launch_bounds__(256) void vq_cvt_frag(
    const float* __restrict__ src, unsigned short* __restrict__ dst) {
  const int c = blockIdx.x * 256 + threadIdx.x;
  const int l = c & 63, h = (c >> 6) & 1, t = c >> 7;
  const float* p =
      src + (size_t)(t * 16 + (l & 15)) * DIM + h * 32 + ((l >> 4) << 3);
  const float4 f0 = *reinterpret_cast<const float4*>(p);
  const float4 f1 = *reinterpret_cast<const float4*>(p + 4);
  ushort4 o0, o1;
  o0.x = f2bf(f0.x); o0.y = f2bf(f0.y); o0.z = f2bf(f0.z); o0.w = f2bf(f0.w);
  o1.x = f2bf(f1.x); o1.y = f2bf(f1.y); o1.z = f2bf(f1.z); o1.w = f2bf(f1.w);
  reinterpret_cast<ushort4*>(dst)[2 * c] = o0;
  reinterpret_cast<ushort4*>(dst)[2 * c + 1] = o1;
}

// --------------------------------------------- pass A: per-row max(dot~) ----
// Block: 4 waves x 128 rows = 512 rows, one 256-code slab staged whole in LDS
// (32 KB, once, no in-loop barriers). Rows in 2 groups of 64 so only 8
// z-fragments (32 VGPR) are live at a time (r5/r6 spill lesson).
__global__ __launch_bounds__(256) void vq_sweep_max(
    const unsigned short* __restrict__ zbf,
    const unsigned short* __restrict__ ebf, float* __restrict__ wsmax) {
  __shared__ char lds[KPART * DIM * 2];   // 32 KB
  const int tid = threadIdx.x;
  const int wid = tid >> 6, l = tid & 63;
  const int rowblk = blockIdx.x & 63, kp = blockIdx.x >> 6;
  const int waveRow = rowblk * 512 + wid * 128;
  const int baseTile = waveRow >> 4;

  const char* slab = (const char*)ebf + (size_t)kp * (KPART * DIM * 2);
#pragma unroll
  for (int c = 0; c < 8; ++c)
    gload_lds16(slab + (c * 256 + tid) * 16, lds + (c * 256 + tid) * 16);
  __syncthreads();

  const f32x4 zero = {0.f, 0.f, 0.f, 0.f};

  for (int g = 0; g < 2; ++g) {           // 2 row-groups of 64 rows (4 tiles)
    bf16x8 bz[4][2];
#pragma unroll
    for (int r = 0; r < 4; ++r)
#pragma unroll
      for (int h = 0; h < 2; ++h)
        bz[r][h] = *reinterpret_cast<const bf16x8*>(
            zbf + ((size_t)((baseTile + g * 4 + r) * 2 + h) * 64 + l) * 8);

    float m4[4] = {-FLT_MAX, -FLT_MAX, -FLT_MAX, -FLT_MAX};
#pragma unroll 2
    for (int s = 0; s < KPART / 16; ++s) {     // 16 codes per step
      const bf16x8 a0 = *reinterpret_cast<const bf16x8*>(lds + s * 2048 + l * 16);
      const bf16x8 a1 =
          *reinterpret_cast<const bf16x8*>(lds + s * 2048 + 1024 + l * 16);
#pragma unroll
      for (int r = 0; r < 4; ++r) {
        f32x4 t = MFMA16(a0, bz[r][0], zero);
        t = MFMA16(a1, bz[r][1], t);
        m4[r] = fmaxf(m4[r], fmaxf(fmaxf(t[0], t[1]), fmaxf(t[2], t[3])));
      }
    }
#pragma unroll
    for (int r = 0; r < 4; ++r) {
      float mm = m4[r];
      mm = fmaxf(mm, __shfl_xor(mm, 16, 64));
      mm = fmaxf(mm, __shfl_xor(mm, 32, 64));
      if (l < 16)
        wsmax[(size_t)kp * N_ROWS + waveRow + (g * 4 + r) * 16 + l] = mm;
    }
  }
}

// ----------------- plan: per-row threshold -> per-slab row lists (compact) ----
__global__ __launch_bounds__(256) void vq_plan(
    const float* __restrict__ wsmax, int* __restrict__ slabCnt,
    int* __restrict__ slabRows) {
  __shared__ int lcnt[KSPLIT], lbase[KSPLIT], lpos[KSPLIT];
  const int tid = threadIdx.x;
  const int row = blockIdx.x * 256 + tid;
  if (tid < KSPLIT) { lcnt[tid] = 0; lpos[tid] = 0; }
  __syncthreads();
  float m = -FLT_MAX;
#pragma unroll
  for (int p = 0; p < KSPLIT; ++p)
    m = fmaxf(m, wsmax[(size_t)p * N_ROWS + row]);
  const float thr = m - DELTA_D;
#pragma unroll
  for (int p = 0; p < KSPLIT; ++p)
    if (wsmax[(size_t)p * N_ROWS + row] >= thr) atomicAdd(&lcnt[p], 1);
  __syncthreads();
  if (tid < KSPLIT) lbase[tid] = atomicAdd(&slabCnt[tid], lcnt[tid]);
  __syncthreads();
#pragma unroll
  for (int p = 0; p < KSPLIT; ++p)
    if (wsmax[(size_t)p * N_ROWS + row] >= thr) {
      const int pos = atomicAdd(&lpos[p], 1);
      slabRows[(size_t)p * N_ROWS + lbase[p] + pos] = row;
    }
}

// --------- slab-scan: exact ref f32 chain over every code of admitted slabs ----
// One thread = one (row, quarter-slab of 64 codes). Lanes carry ROWS; e
// addresses are wave-uniform (s_load path, SGPR-resident). z row is staged
// in LDS (row stride 68 floats = 272 B, odd multiple of 16 B -> 32 lanes'
// ds_read_b128 of chunk i hit 32 distinct bank groups: conflict-free), and
// the k-loop reads ONE float4 chunk at a time -> live set ~10 VGPR. This
// removes the global-z rematerialization the compiler did in r7/r8 (VGPR=40
// + 13 MB scratch-write storm) — LDS can't be "re-loaded from global".
// Merge via lex-packed atomicMin (min score, tie -> min code = numpy
// first-occurrence). fma chain d-ascending per code — bit-exact vs reference.
__global__ __launch_bounds__(256, 2) void vq_slabscan(
    const float* __restrict__ z, const float* __restrict__ e,
    const float* __restrict__ zsq, const int* __restrict__ slabCnt,
    const int* __restrict__ slabRows, unsigned long long* __restrict__ best) {
  __shared__ float lz[256 * 68];           // 68 KB, 2 blocks/CU
  float* const myz = lz + (size_t)threadIdx.x * 68;
  const int kp = blockIdx.x >> 6;          // 32 slabs x 4 quarters x 16 chunks
  const int quarter = (blockIdx.x >> 4) & 3;
  const int blk = blockIdx.x & 15;
  const int cnt = slabCnt[kp];
  const int kofs = kp * KPART + quarter * QS;
  const float* const eb = e + (size_t)kofs * DIM;

  for (int ri = blk * 256 + threadIdx.x; ri < cnt; ri += 16 * 256) {
    const int row = slabRows[(size_t)kp * N_ROWS + ri];
    const float4* zp = reinterpret_cast<const float4*>(z + (size_t)row * DIM);
#pragma unroll
    for (int i = 0; i < 16; ++i)
      *reinterpret_cast<float4*>(myz + 4 * i) = zp[i];
    const float zq = zsq[row];
    float bs = FLT_MAX;
    int bk = 0;
    for (int k = 0; k < QS; k += 2) {      // 2 interleaved exact chains
      const float* e0 = eb + (size_t)k * DIM;
      const float* e1 = e0 + DIM;
      float d0 = 0.f, d1 = 0.f;
#pragma unroll
      for (int i = 0; i < 16; ++i) {       // chunks ascending -> d ascending
        const float4 zi = *reinterpret_cast<const float4*>(myz + 4 * i);
        d0 = fmaf(zi.x, e0[4 * i + 0], d0);
        d0 = fmaf(zi.y, e0[4 * i + 1], d0);
        d0 = fmaf(zi.z, e0[4 * i + 2], d0);
        d0 = fmaf(zi.w, e0[4 * i + 3], d0);
        d1 = fmaf(zi.x, e1[4 * i + 0], d1);
        d1 = fmaf(zi.y, e1[4 * i + 1], d1);
        d1 = fmaf(zi.z, e1[4 * i + 2], d1);
        d1 = fmaf(zi.w, e1[4 * i + 3], d1);
      }
      const float s0 = fmaf(-2.f, d0, zq);   // bit-exact vs reference
      const float s1 = fmaf(-2.f, d1, zq);
      if (s0 < bs) { bs = s0; bk = k; }      // ascending k, strict <
      if (s1 < bs) { bs = s1; bk = k + 1; }
    }
    unsigned u = __float_as_uint(bs);
    const unsigned enc = (u >> 31) ? ~u : (u | 0x80000000u);
    const unsigned long long pack =
        ((unsigned long long)enc << 32) | (unsigned)(kofs + bk);
    atomicMin(best + row, pack);
  }
}

// -------------------------------------------------------- gather + loss ----
__global__ __launch_bounds__(256) void vq_gather_loss(
    const float* __restrict__ z, const float* __restrict__ e,
    const unsigned long long* __restrict__ best, float* __restrict__ qout,
    float* __restrict__ idxf, float* __restrict__ partials) {
  const int tid = threadIdx.x;
  const int rl = tid >> 4;
  const int t = tid & 15;
  const int row = blockIdx.x * 16 + rl;
  const int id = (int)(unsigned)(best[row] & 0xFFFFFFFFu);
  if (t == 0) idxf[row] = (float)id;
  const float4 qv =
      *reinterpret_cast<const float4*>(e + (size_t)id * DIM + 4 * t);
  const float4 zv =
      *reinterpret_cast<const float4*>(z + (size_t)row * DIM + 4 * t);
  *reinterpret_cast<float4*>(qout + (size_t)row * DIM + 4 * t) = qv;
  const float dx = zv.x - qv.x, dy = zv.y - qv.y;
  const float dz = zv.z - qv.z, dw = zv.w - qv.w;
  float s = dx * dx + dy * dy + dz * dz + dw * dw;

  __shared__ float red[256];
  red[tid] = s;
  __syncthreads();
  for (int off = 128; off > 0; off >>= 1) {
    if (tid < off) red[tid] += red[tid + off];
    __syncthreads();
  }
  if (tid == 0) partials[blockIdx.x] = red[0];
}

// ------------------------------------------------------------ finalize ----
__global__ __launch_bounds__(256) void vq_finalize(
    const float* __restrict__ partials, float* __restrict__ loss_out) {
  const int tid = threadIdx.x;
  float s = 0.f;
#pragma unroll
  for (int j = 0; j < 8; ++j) s += partials[tid + 256 * j];
  __shared__ float red[256];
  red[tid] = s;
  __syncthreads();
  for (int off = 128; off > 0; off >>= 1) {
    if (tid < off) red[tid] += red[tid + off];
    __syncthreads();
  }
  if (tid == 0) {
    const float loss = red[0] / (float)(N_ROWS * DIM);
    loss_out[0] = loss;
    loss_out[1] = loss;
  }
}

extern "C" void kernel_launch(void* const* d_in, const int* in_sizes, int n_in,
                              void* d_out, int out_size, void* d_ws,
                              size_t ws_size, hipStream_t stream) {
  const float* z = (const float*)d_in[0];   // [32768, 64]
  const float* e = (const float*)d_in[1];   // [8192, 64]
  float* out = (float*)d_out;
  float* qout = out;
  float* loss_out = out + (size_t)N_ROWS * DIM;
  float* idxf_out = loss_out + 2;

  char* ws = (char*)d_ws;
  float* partials = (float*)(ws + WS_PARTIALS);
  float* zsq = (float*)(ws + WS_ZSQ);
  unsigned short* ebf = (unsigned short*)(ws + WS_EBF);
  unsigned short* zbf = (unsigned short*)(ws + WS_ZBF);
  float* wsmax = (float*)(ws + WS_MAX);
  int* slabCnt = (int*)(ws + WS_SLABCNT);
  int* slabRows = (int*)(ws + WS_SLABROWS);   // overlays zbf (dead after sweep)
  unsigned long long* best = (unsigned long long*)(ws + WS_BEST);

  hipMemsetAsync(slabCnt, 0, KSPLIT * sizeof(int), stream);
  hipMemsetAsync(best, 0xFF, N_ROWS * sizeof(unsigned long long), stream);
  vq_zsq<<<N_ROWS / 256, 256, 0, stream>>>(z, zsq);
  vq_cvt_frag<<<(K_CODES * DIM / 8) / 256, 256, 0, stream>>>(e, ebf);
  vq_cvt_frag<<<(N_ROWS * DIM / 8) / 256, 256, 0, stream>>>(z, zbf);
  vq_sweep_max<<<64 * KSPLIT, 256, 0, stream>>>(zbf, ebf, wsmax);
  vq_plan<<<N_ROWS / 256, 256, 0, stream>>>(wsmax, slabCnt, slabRows);
  vq_slabscan<<<KSPLIT * 4 * 16, 256, 0, stream>>>(z, e, zsq, slabCnt,
                                                   slabRows, best);
  vq_gather_loss<<<N_ROWS / 16, 256, 0, stream>>>(z, e, best, qout, idxf_out,
                                                  partials);
  vq_finalize<<<1, 256, 0, stream>>>(partials, loss_out);
}

// Round 10
// 230.159 us; speedup vs baseline: 1.1958x; 1.1958x over previous
//
#include <hip/hip_runtime.h>
#include <float.h>

#define N_ROWS  32768
#define K_CODES 8192
#define DIM     64
#define KSPLIT  32
#define KPART   (K_CODES / KSPLIT)   // 256 codes per slab
#define QS      (KPART / 4)          // 64 codes per quarter-slab (= wave width)
#define DELTA_D 2e-4f

typedef __attribute__((ext_vector_type(8))) short bf16x8;
typedef __attribute__((ext_vector_type(4))) float f32x4;

// ws layout (bytes):
#define WS_PARTIALS 0          // 2048 f    (8 KB)
#define WS_ZSQ      8192       // 32768 f   (128 KB)
#define WS_EBF      139264     // 8192*64 bf16 frag-order (1 MB)
#define WS_ZBF      1187840    // 32768*64 bf16 frag-order (4 MB)
#define WS_SLABROWS 1187840    // [32][32768] i (4 MB) — overlays ZBF (dead after sweep)
#define WS_MAX      5382144    // [32][32768] f (4 MB)
#define WS_SLABCNT  9576448    // 32 i (pad to 512 B)
#define WS_BEST     9576960    // 32768 u64 (256 KB) -> total ~9.84 MB

__device__ __forceinline__ unsigned short f2bf(float f) {
  unsigned u = __float_as_uint(f);
  u = (u + 0x7fffu + ((u >> 16) & 1u)) >> 16;   // RNE, finite inputs
  return (unsigned short)u;
}

__device__ __forceinline__ void gload_lds16(const void* g, void* l) {
  typedef const __attribute__((address_space(1))) unsigned int* gp_t;
  typedef __attribute__((address_space(3))) unsigned int* lp_t;
  __builtin_amdgcn_global_load_lds((gp_t)g, (lp_t)l, 16, 0, 0);
}

#define MFMA16(a, b, c) __builtin_amdgcn_mfma_f32_16x16x32_bf16((a), (b), (c), 0, 0, 0)

// ----------------------------------------------------------------- z_sq ----
// Bit-exact numpy pairwise sum of z*z over 64 elems (validated round 2).
__global__ __launch_bounds__(256) void vq_zsq(const float* __restrict__ z,
                                              float* __restrict__ zsq) {
  const int row = blockIdx.x * 256 + threadIdx.x;
  const float4* z4 = reinterpret_cast<const float4*>(z + (size_t)row * DIM);
  float r[8];
  {
    const float4 v0 = z4[0], v1 = z4[1];
    r[0] = __fmul_rn(v0.x, v0.x); r[1] = __fmul_rn(v0.y, v0.y);
    r[2] = __fmul_rn(v0.z, v0.z); r[3] = __fmul_rn(v0.w, v0.w);
    r[4] = __fmul_rn(v1.x, v1.x); r[5] = __fmul_rn(v1.y, v1.y);
    r[6] = __fmul_rn(v1.z, v1.z); r[7] = __fmul_rn(v1.w, v1.w);
  }
#pragma unroll
  for (int i = 1; i < 8; ++i) {
    const float4 v0 = z4[2 * i], v1 = z4[2 * i + 1];
    r[0] = __fadd_rn(r[0], __fmul_rn(v0.x, v0.x));
    r[1] = __fadd_rn(r[1], __fmul_rn(v0.y, v0.y));
    r[2] = __fadd_rn(r[2], __fmul_rn(v0.z, v0.z));
    r[3] = __fadd_rn(r[3], __fmul_rn(v0.w, v0.w));
    r[4] = __fadd_rn(r[4], __fmul_rn(v1.x, v1.x));
    r[5] = __fadd_rn(r[5], __fmul_rn(v1.y, v1.y));
    r[6] = __fadd_rn(r[6], __fmul_rn(v1.z, v1.z));
    r[7] = __fadd_rn(r[7], __fmul_rn(v1.w, v1.w));
  }
  zsq[row] = __fadd_rn(
      __fadd_rn(__fadd_rn(r[0], r[1]), __fadd_rn(r[2], r[3])),
      __fadd_rn(__fadd_rn(r[4], r[5]), __fadd_rn(r[6], r[7])));
}

// ------------------------------------------------- cvt to fragment order ----
// chunk c (8 bf16 = 16B): l=c&63, h=(c>>6)&1, t=c>>7
//   dst[c] = src[idx = t*16 + (l&15)][d = h*32 + (l>>4)*8 .. +8]
__global__ __launch_bounds__(256) void vq_cvt_frag(
    const float* __restrict__ src, unsigned short* __restrict__ dst) {
  const int c = blockIdx.x * 256 + threadIdx.x;
  const int l = c & 63, h = (c >> 6) & 1, t = c >> 7;
  const float* p =
      src + (size_t)(t * 16 + (l & 15)) * DIM + h * 32 + ((l >> 4) << 3);
  const float4 f0 = *reinterpret_cast<const float4*>(p);
  const float4 f1 = *reinterpret_cast<const float4*>(p + 4);
  ushort4 o0, o1;
  o0.x = f2bf(f0.x); o0.y = f2bf(f0.y); o0.z = f2bf(f0.z); o0.w = f2bf(f0.w);
  o1.x = f2bf(f1.x); o1.y = f2bf(f1.y); o1.z = f2bf(f1.z); o1.w = f2bf(f1.w);
  reinterpret_cast<ushort4*>(dst)[2 * c] = o0;
  reinterpret_cast<ushort4*>(dst)[2 * c + 1] = o1;
}

// --------------------------------------------- pass A: per-row max(dot~) ----
// Block: 4 waves x 128 rows = 512 rows, one 256-code slab staged whole in LDS
// (32 KB, once, no in-loop barriers). Rows in 2 groups of 64 so only 8
// z-fragments (32 VGPR) are live at a time (r5/r6 spill lesson).
__global__ __launch_bounds__(256) void vq_sweep_max(
    const unsigned short* __restrict__ zbf,
    const unsigned short* __restrict__ ebf, float* __restrict__ wsmax) {
  __shared__ char lds[KPART * DIM * 2];   // 32 KB
  const int tid = threadIdx.x;
  const int wid = tid >> 6, l = tid & 63;
  const int rowblk = blockIdx.x & 63, kp = blockIdx.x >> 6;
  const int waveRow = rowblk * 512 + wid * 128;
  const int baseTile = waveRow >> 4;

  const char* slab = (const char*)ebf + (size_t)kp * (KPART * DIM * 2);
#pragma unroll
  for (int c = 0; c < 8; ++c)
    gload_lds16(slab + (c * 256 + tid) * 16, lds + (c * 256 + tid) * 16);
  __syncthreads();

  const f32x4 zero = {0.f, 0.f, 0.f, 0.f};

  for (int g = 0; g < 2; ++g) {           // 2 row-groups of 64 rows (4 tiles)
    bf16x8 bz[4][2];
#pragma unroll
    for (int r = 0; r < 4; ++r)
#pragma unroll
      for (int h = 0; h < 2; ++h)
        bz[r][h] = *reinterpret_cast<const bf16x8*>(
            zbf + ((size_t)((baseTile + g * 4 + r) * 2 + h) * 64 + l) * 8);

    float m4[4] = {-FLT_MAX, -FLT_MAX, -FLT_MAX, -FLT_MAX};
#pragma unroll 2
    for (int s = 0; s < KPART / 16; ++s) {     // 16 codes per step
      const bf16x8 a0 = *reinterpret_cast<const bf16x8*>(lds + s * 2048 + l * 16);
      const bf16x8 a1 =
          *reinterpret_cast<const bf16x8*>(lds + s * 2048 + 1024 + l * 16);
#pragma unroll
      for (int r = 0; r < 4; ++r) {
        f32x4 t = MFMA16(a0, bz[r][0], zero);
        t = MFMA16(a1, bz[r][1], t);
        m4[r] = fmaxf(m4[r], fmaxf(fmaxf(t[0], t[1]), fmaxf(t[2], t[3])));
      }
    }
#pragma unroll
    for (int r = 0; r < 4; ++r) {
      float mm = m4[r];
      mm = fmaxf(mm, __shfl_xor(mm, 16, 64));
      mm = fmaxf(mm, __shfl_xor(mm, 32, 64));
      if (l < 16)
        wsmax[(size_t)kp * N_ROWS + waveRow + (g * 4 + r) * 16 + l] = mm;
    }
  }
}

// ----------------- plan: per-row threshold -> per-slab row lists (compact) ----
__global__ __launch_bounds__(256) void vq_plan(
    const float* __restrict__ wsmax, int* __restrict__ slabCnt,
    int* __restrict__ slabRows) {
  __shared__ int lcnt[KSPLIT], lbase[KSPLIT], lpos[KSPLIT];
  const int tid = threadIdx.x;
  const int row = blockIdx.x * 256 + tid;
  if (tid < KSPLIT) { lcnt[tid] = 0; lpos[tid] = 0; }
  __syncthreads();
  float m = -FLT_MAX;
#pragma unroll
  for (int p = 0; p < KSPLIT; ++p)
    m = fmaxf(m, wsmax[(size_t)p * N_ROWS + row]);
  const float thr = m - DELTA_D;
#pragma unroll
  for (int p = 0; p < KSPLIT; ++p)
    if (wsmax[(size_t)p * N_ROWS + row] >= thr) atomicAdd(&lcnt[p], 1);
  __syncthreads();
  if (tid < KSPLIT) lbase[tid] = atomicAdd(&slabCnt[tid], lcnt[tid]);
  __syncthreads();
#pragma unroll
  for (int p = 0; p < KSPLIT; ++p)
    if (wsmax[(size_t)p * N_ROWS + row] >= thr) {
      const int pos = atomicAdd(&lpos[p], 1);
      slabRows[(size_t)p * N_ROWS + lbase[p] + pos] = row;
    }
}

// --------- slab-scan: exact ref f32 chain over every code of admitted slabs ----
// NEW STRUCTURE (r9 lesson: any per-thread z copy is fatal — regs blow the
// budget, scratch streams HBM, per-thread LDS kills occupancy):
//   one WAVE per (row, quarter-slab), LANE = CODE.
//   * z row is wave-uniform -> readfirstlane(row) forces z loads onto the
//     SCALAR path (SGPRs, shared by all 64 lanes). No per-lane z storage.
//   * e quarter-slab (64 codes x 64 f32) staged once per block into LDS,
//     padded to 68 f/code: chunk addr/16 = 17*l + i, 17 coprime 32 ->
//     conflict-free ds_read_b128 (l and l+32 alias = free 2-way).
//   * per lane: strictly d-ascending fmaf chain for its code (bit-exact,
//     validated r2), then 6-step shfl lex-min reduce, 1 atomicMin per wave.
// LDS 17.4 KB, tiny VGPR -> ~8 blocks/CU.
__global__ __launch_bounds__(256) void vq_slabscan(
    const float* __restrict__ z, const float* __restrict__ e,
    const float* __restrict__ zsq, const int* __restrict__ slabCnt,
    const int* __restrict__ slabRows, unsigned long long* __restrict__ best) {
  __shared__ float lz[QS * 68];            // 17408 B
  const int tid = threadIdx.x;
  const int l = tid & 63, wid = tid >> 6;
  const int kp = blockIdx.x >> 6;          // 32 slabs x 4 quarters x 16 chunks
  const int quarter = (blockIdx.x >> 4) & 3;
  const int blk = blockIdx.x & 15;
  const int kofs = kp * KPART + quarter * QS;

  // stage quarter (64 codes x 64 f32 = 16 KB, contiguous in e) into padded LDS
  const float4* esrc = reinterpret_cast<const float4*>(e + (size_t)kofs * DIM);
#pragma unroll
  for (int j = 0; j < 4; ++j) {
    const int c = tid + 256 * j;           // chunk 0..1023
    *reinterpret_cast<float4*>(&lz[(c >> 4) * 68 + 4 * (c & 15)]) = esrc[c];
  }
  __syncthreads();

  const int cnt = slabCnt[kp];
  const unsigned mycode = (unsigned)(kofs + l);
  for (int ri = blk * 4 + wid; ri < cnt; ri += 64) {
    const int row =
        __builtin_amdgcn_readfirstlane(slabRows[(size_t)kp * N_ROWS + ri]);
    const float* zr = z + (size_t)row * DIM;   // uniform -> scalar loads
    const float zq = zsq[row];
    float d0 = 0.f;
#pragma unroll
    for (int i = 0; i < 16; ++i) {         // chunks ascending -> d ascending
      const float4 zi = *reinterpret_cast<const float4*>(zr + 4 * i);
      const float4 ei = *reinterpret_cast<const float4*>(&lz[l * 68 + 4 * i]);
      d0 = fmaf(zi.x, ei.x, d0);
      d0 = fmaf(zi.y, ei.y, d0);
      d0 = fmaf(zi.z, ei.z, d0);
      d0 = fmaf(zi.w, ei.w, d0);
    }
    const float s0 = fmaf(-2.f, d0, zq);   // bit-exact vs reference
    const unsigned u = __float_as_uint(s0);
    const unsigned enc = (u >> 31) ? ~u : (u | 0x80000000u);
    unsigned long long pack = ((unsigned long long)enc << 32) | mycode;
#pragma unroll
    for (int off = 32; off > 0; off >>= 1) {   // lex min: score, then code
      const unsigned long long o = __shfl_xor(pack, off, 64);
      if (o < pack) pack = o;
    }
    if (l == 0) atomicMin(best + row, pack);
  }
}

// -------------------------------------------------------- gather + loss ----
__global__ __launch_bounds__(256) void vq_gather_loss(
    const float* __restrict__ z, const float* __restrict__ e,
    const unsigned long long* __restrict__ best, float* __restrict__ qout,
    float* __restrict__ idxf, float* __restrict__ partials) {
  const int tid = threadIdx.x;
  const int rl = tid >> 4;
  const int t = tid & 15;
  const int row = blockIdx.x * 16 + rl;
  const int id = (int)(unsigned)(best[row] & 0xFFFFFFFFu);
  if (t == 0) idxf[row] = (float)id;
  const float4 qv =
      *reinterpret_cast<const float4*>(e + (size_t)id * DIM + 4 * t);
  const float4 zv =
      *reinterpret_cast<const float4*>(z + (size_t)row * DIM + 4 * t);
  *reinterpret_cast<float4*>(qout + (size_t)row * DIM + 4 * t) = qv;
  const float dx = zv.x - qv.x, dy = zv.y - qv.y;
  const float dz = zv.z - qv.z, dw = zv.w - qv.w;
  float s = dx * dx + dy * dy + dz * dz + dw * dw;

  __shared__ float red[256];
  red[tid] = s;
  __syncthreads();
  for (int off = 128; off > 0; off >>= 1) {
    if (tid < off) red[tid] += red[tid + off];
    __syncthreads();
  }
  if (tid == 0) partials[blockIdx.x] = red[0];
}

// ------------------------------------------------------------ finalize ----
__global__ __launch_bounds__(256) void vq_finalize(
    const float* __restrict__ partials, float* __restrict__ loss_out) {
  const int tid = threadIdx.x;
  float s = 0.f;
#pragma unroll
  for (int j = 0; j < 8; ++j) s += partials[tid + 256 * j];
  __shared__ float red[256];
  red[tid] = s;
  __syncthreads();
  for (int off = 128; off > 0; off >>= 1) {
    if (tid < off) red[tid] += red[tid + off];
    __syncthreads();
  }
  if (tid == 0) {
    const float loss = red[0] / (float)(N_ROWS * DIM);
    loss_out[0] = loss;
    loss_out[1] = loss;
  }
}

extern "C" void kernel_launch(void* const* d_in, const int* in_sizes, int n_in,
                              void* d_out, int out_size, void* d_ws,
                              size_t ws_size, hipStream_t stream) {
  const float* z = (const float*)d_in[0];   // [32768, 64]
  const float* e = (const float*)d_in[1];   // [8192, 64]
  float* out = (float*)d_out;
  float* qout = out;
  float* loss_out = out + (size_t)N_ROWS * DIM;
  float* idxf_out = loss_out + 2;

  char* ws = (char*)d_ws;
  float* partials = (float*)(ws + WS_PARTIALS);
  float* zsq = (float*)(ws + WS_ZSQ);
  unsigned short* ebf = (unsigned short*)(ws + WS_EBF);
  unsigned short* zbf = (unsigned short*)(ws + WS_ZBF);
  float* wsmax = (float*)(ws + WS_MAX);
  int* slabCnt = (int*)(ws + WS_SLABCNT);
  int* slabRows = (int*)(ws + WS_SLABROWS);   // overlays zbf (dead after sweep)
  unsigned long long* best = (unsigned long long*)(ws + WS_BEST);

  hipMemsetAsync(slabCnt, 0, KSPLIT * sizeof(int), stream);
  hipMemsetAsync(best, 0xFF, N_ROWS * sizeof(unsigned long long), stream);
  vq_zsq<<<N_ROWS / 256, 256, 0, stream>>>(z, zsq);
  vq_cvt_frag<<<(K_CODES * DIM / 8) / 256, 256, 0, stream>>>(e, ebf);
  vq_cvt_frag<<<(N_ROWS * DIM / 8) / 256, 256, 0, stream>>>(z, zbf);
  vq_sweep_max<<<64 * KSPLIT, 256, 0, stream>>>(zbf, ebf, wsmax);
  vq_plan<<<N_ROWS / 256, 256, 0, stream>>>(wsmax, slabCnt, slabRows);
  vq_slabscan<<<KSPLIT * 4 * 16, 256, 0, stream>>>(z, e, zsq, slabCnt,
                                                   slabRows, best);
  vq_gather_loss<<<N_ROWS / 16, 256, 0, stream>>>(z, e, best, qout, idxf_out,
                                                  partials);
  vq_finalize<<<1, 256, 0, stream>>>(partials, loss_out);
}

// Round 13
// 148.186 us; speedup vs baseline: 1.8572x; 1.5532x over previous
//
#include <hip/hip_runtime.h>
#include <float.h>

#define N_ROWS  32768
#define K_CODES 8192
#define DIM     64
#define KSPLIT  32
#define KPART   (K_CODES / KSPLIT)   // 256 codes per slab
#define TILEK   64                   // codes per LDS tile (8 KB)
#define NTILES  (KPART / TILEK)      // 4
#define TSTEPS  (TILEK / 16)         // 4 fragment-steps per tile
#define CAP     32
#define DELTA_D 2e-4f

typedef __attribute__((ext_vector_type(8))) short bf16x8;
typedef __attribute__((ext_vector_type(4))) float f32x4;

// ws layout (bytes) — EXACT r6-proven map (total 9969664):
#define WS_PARTIALS 0          // 2048 f    (8 KB)   -> 8192
#define WS_ZSQ      8192       // 32768 f   (128 KB) -> 139264
#define WS_IDX      139264     // 32768 i   (128 KB) -> 270336
#define WS_EBF      270336     // 8192*64 bf16 frag (1 MB) -> 1318912
#define WS_ZBF      1318912    // 32768*64 bf16 frag (4 MB) -> 5513216
#define WS_MAX      5513216    // [32][32768] f (4 MB) -> 9707520
#define WS_CANDS    5513216    // 32768*32 i (4 MB) — overlays WS_MAX (dead after thr)
#define WS_THR      9707520    // 32768 f (128 KB) -> 9838592
#define WS_CNT      9838592    // 32768 i (128 KB) -> 9969664 total

__device__ __forceinline__ unsigned short f2bf(float f) {
  unsigned u = __float_as_uint(f);
  u = (u + 0x7fffu + ((u >> 16) & 1u)) >> 16;   // RNE, finite inputs
  return (unsigned short)u;
}

__device__ __forceinline__ void gload_lds16(const void* g, void* l) {
  typedef const __attribute__((address_space(1))) unsigned int* gp_t;
  typedef __attribute__((address_space(3))) unsigned int* lp_t;
  __builtin_amdgcn_global_load_lds((gp_t)g, (lp_t)l, 16, 0, 0);
}

#define MFMA16(a, b, c) __builtin_amdgcn_mfma_f32_16x16x32_bf16((a), (b), (c), 0, 0, 0)

// ----------------------------------------------------------------- z_sq ----
// Bit-exact numpy pairwise sum of z*z over 64 elems (validated round 2).
__global__ __launch_bounds__(256) void vq_zsq(const float* __restrict__ z,
                                              float* __restrict__ zsq) {
  const int row = blockIdx.x * 256 + threadIdx.x;
  const float4* z4 = reinterpret_cast<const float4*>(z + (size_t)row * DIM);
  float r[8];
  {
    const float4 v0 = z4[0], v1 = z4[1];
    r[0] = __fmul_rn(v0.x, v0.x); r[1] = __fmul_rn(v0.y, v0.y);
    r[2] = __fmul_rn(v0.z, v0.z); r[3] = __fmul_rn(v0.w, v0.w);
    r[4] = __fmul_rn(v1.x, v1.x); r[5] = __fmul_rn(v1.y, v1.y);
    r[6] = __fmul_rn(v1.z, v1.z); r[7] = __fmul_rn(v1.w, v1.w);
  }
#pragma unroll
  for (int i = 1; i < 8; ++i) {
    const float4 v0 = z4[2 * i], v1 = z4[2 * i + 1];
    r[0] = __fadd_rn(r[0], __fmul_rn(v0.x, v0.x));
    r[1] = __fadd_rn(r[1], __fmul_rn(v0.y, v0.y));
    r[2] = __fadd_rn(r[2], __fmul_rn(v0.z, v0.z));
    r[3] = __fadd_rn(r[3], __fmul_rn(v0.w, v0.w));
    r[4] = __fadd_rn(r[4], __fmul_rn(v1.x, v1.x));
    r[5] = __fadd_rn(r[5], __fmul_rn(v1.y, v1.y));
    r[6] = __fadd_rn(r[6], __fmul_rn(v1.z, v1.z));
    r[7] = __fadd_rn(r[7], __fmul_rn(v1.w, v1.w));
  }
  zsq[row] = __fadd_rn(
      __fadd_rn(__fadd_rn(r[0], r[1]), __fadd_rn(r[2], r[3])),
      __fadd_rn(__fadd_rn(r[4], r[5]), __fadd_rn(r[6], r[7])));
}

// ------------------------------------------------- cvt to fragment order ----
// chunk c (8 bf16 = 16B): l=c&63, h=(c>>6)&1, t=c>>7
//   dst[c] = src[idx = t*16 + (l&15)][d = h*32 + (l>>4)*8 .. +8]
__global__ __launch_bounds__(256) void vq_cvt_frag(
    const float* __restrict__ src, unsigned short* __restrict__ dst) {
  const int c = blockIdx.x * 256 + threadIdx.x;
  const int l = c & 63, h = (c >> 6) & 1, t = c >> 7;
  const float* p =
      src + (size_t)(t * 16 + (l & 15)) * DIM + h * 32 + ((l >> 4) << 3);
  const float4 f0 = *reinterpret_cast<const float4*>(p);
  const float4 f1 = *reinterpret_cast<const float4*>(p + 4);
  ushort4 o0, o1;
  o0.x = f2bf(f0.x); o0.y = f2bf(f0.y); o0.z = f2bf(f0.z); o0.w = f2bf(f0.w);
  o1.x = f2bf(f1.x); o1.y = f2bf(f1.y); o1.z = f2bf(f1.z); o1.w = f2bf(f1.w);
  reinterpret_cast<ushort4*>(dst)[2 * c] = o0;
  reinterpret_cast<ushort4*>(dst)[2 * c + 1] = o1;
}

// --------------------------------------------- pass A: per-row max(dot~) ----
// r7-r10 proven: 4 waves x 128 rows = 512 rows/block, one 256-code slab in
// LDS (staged once), rows in 2 groups of 4 tiles (32 VGPR of z-frags live).
__global__ __launch_bounds__(256) void vq_sweep_max(
    const unsigned short* __restrict__ zbf,
    const unsigned short* __restrict__ ebf, float* __restrict__ wsmax) {
  __shared__ char lds[KPART * DIM * 2];   // 32 KB
  const int tid = threadIdx.x;
  const int wid = tid >> 6, l = tid & 63;
  const int rowblk = blockIdx.x & 63, kp = blockIdx.x >> 6;
  const int waveRow = rowblk * 512 + wid * 128;
  const int baseTile = waveRow >> 4;

  const char* slab = (const char*)ebf + (size_t)kp * (KPART * DIM * 2);
#pragma unroll
  for (int c = 0; c < 8; ++c)
    gload_lds16(slab + (c * 256 + tid) * 16, lds + (c * 256 + tid) * 16);
  __syncthreads();

  const f32x4 zero = {0.f, 0.f, 0.f, 0.f};

  for (int g = 0; g < 2; ++g) {
    bf16x8 bz[4][2];
#pragma unroll
    for (int r = 0; r < 4; ++r)
#pragma unroll
      for (int h = 0; h < 2; ++h)
        bz[r][h] = *reinterpret_cast<const bf16x8*>(
            zbf + ((size_t)((baseTile + g * 4 + r) * 2 + h) * 64 + l) * 8);

    float m4[4] = {-FLT_MAX, -FLT_MAX, -FLT_MAX, -FLT_MAX};
#pragma unroll 2
    for (int s = 0; s < KPART / 16; ++s) {
      const bf16x8 a0 = *reinterpret_cast<const bf16x8*>(lds + s * 2048 + l * 16);
      const bf16x8 a1 =
          *reinterpret_cast<const bf16x8*>(lds + s * 2048 + 1024 + l * 16);
#pragma unroll
      for (int r = 0; r < 4; ++r) {
        f32x4 t = MFMA16(a0, bz[r][0], zero);
        t = MFMA16(a1, bz[r][1], t);
        m4[r] = fmaxf(m4[r], fmaxf(fmaxf(t[0], t[1]), fmaxf(t[2], t[3])));
      }
    }
#pragma unroll
    for (int r = 0; r < 4; ++r) {
      float mm = m4[r];
      mm = fmaxf(mm, __shfl_xor(mm, 16, 64));
      mm = fmaxf(mm, __shfl_xor(mm, 32, 64));
      if (l < 16)
        wsmax[(size_t)kp * N_ROWS + waveRow + (g * 4 + r) * 16 + l] = mm;
    }
  }
}

// -------------------------------------- reduce per-slab maxima to thr ----
// r5/r6-proven.
__global__ __launch_bounds__(256) void vq_thr(const float* __restrict__ wsmax,
                                              float* __restrict__ thr) {
  const int row = blockIdx.x * 256 + threadIdx.x;
  float m = -FLT_MAX;
#pragma unroll
  for (int p = 0; p < KSPLIT; ++p)
    m = fmaxf(m, wsmax[(size_t)p * N_ROWS + row]);
  thr[row] = m - DELTA_D;
}

// ----------------------------------- pass B: collect near-max candidates ----
// r5/r6-proven (r6: 61.5 us, VGPR 60, zero spill/conflicts).
__global__ __launch_bounds__(256, 4) void vq_sweep_collect(
    const unsigned short* __restrict__ zbf,
    const unsigned short* __restrict__ ebf, const float* __restrict__ thrbuf,
    int* __restrict__ cnt, int* __restrict__ cands) {
  __shared__ f32x4 lds4[1024];
  char* lds = (char*)lds4;
  const int tid = threadIdx.x;
  const int wid = tid >> 6, l = tid & 63;
  const int l15 = l & 15, lg = l >> 4;
  const int rowblk = blockIdx.x & 63, kp = blockIdx.x >> 6;
  const int kb = kp * KPART;
  const int waveRow = rowblk * 512 + wid * 128;
  const int baseTile = waveRow >> 4;

  bf16x8 bz[8][2];
#pragma unroll
  for (int rt = 0; rt < 8; ++rt)
#pragma unroll
    for (int h = 0; h < 2; ++h)
      bz[rt][h] = *reinterpret_cast<const bf16x8*>(
          zbf + ((size_t)((baseTile + rt) * 2 + h) * 64 + l) * 8);

  float thr[8];
#pragma unroll
  for (int rt = 0; rt < 8; ++rt)
    thr[rt] = thrbuf[waveRow + rt * 16 + l15];

  const char* slab = (const char*)ebf + (size_t)kp * (KPART * DIM * 2);
#pragma unroll
  for (int c = 0; c < 2; ++c)
    gload_lds16(slab + (wid * 2 + c) * 1024 + l * 16,
                lds + (wid * 2 + c) * 1024);
  __syncthreads();

  const f32x4 zero = {0.f, 0.f, 0.f, 0.f};

  for (int tk = 0; tk < NTILES; ++tk) {
    char* cur = lds + (tk & 1) * 8192;
    if (tk + 1 < NTILES) {
      char* nxt = lds + ((tk + 1) & 1) * 8192;
      const char* src = slab + (size_t)(tk + 1) * 8192;
#pragma unroll
      for (int c = 0; c < 2; ++c)
        gload_lds16(src + (wid * 2 + c) * 1024 + l * 16,
                    nxt + (wid * 2 + c) * 1024);
    }
#pragma unroll
    for (int s = 0; s < TSTEPS; ++s) {
      const bf16x8 a0 = *reinterpret_cast<const bf16x8*>(cur + s * 2048 + l * 16);
      const bf16x8 a1 =
          *reinterpret_cast<const bf16x8*>(cur + s * 2048 + 1024 + l * 16);
#pragma unroll
      for (int rt = 0; rt < 8; ++rt) {
        f32x4 t = MFMA16(a0, bz[rt][0], zero);
        t = MFMA16(a1, bz[rt][1], t);   // bit-identical to pass A
        if (t[0] >= thr[rt] || t[1] >= thr[rt] || t[2] >= thr[rt] ||
            t[3] >= thr[rt]) {          // rare
          const int row = waveRow + rt * 16 + l15;
          const int kbase = kb + tk * TILEK + s * 16 + lg * 4;
#pragma unroll
          for (int i = 0; i < 4; ++i)
            if (t[i] >= thr[rt]) {
              const int pos = atomicAdd(&cnt[row], 1);
              if (pos < CAP) cands[(size_t)row * CAP + pos] = kbase + i;
            }
        }
      }
    }
    __syncthreads();
  }
}

// ------------------------- resolve: exact ref chain on candidates only ----
// r4/r6-proven thread-per-row version (+ harmless k range guard).
__global__ __launch_bounds__(256) void vq_resolve(
    const float* __restrict__ z, const float* __restrict__ e,
    const float* __restrict__ zsq, const int* __restrict__ cnt,
    const int* __restrict__ cands, int* __restrict__ oidx,
    float* __restrict__ oidxf) {
  const int row = blockIdx.x * 256 + threadIdx.x;
  float zr[DIM];
#pragma unroll
  for (int t = 0; t < DIM / 4; ++t) {
    const float4 v = reinterpret_cast<const float4*>(z + (size_t)row * DIM)[t];
    zr[4 * t + 0] = v.x; zr[4 * t + 1] = v.y;
    zr[4 * t + 2] = v.z; zr[4 * t + 3] = v.w;
  }
  const float zq = zsq[row];
  int c = cnt[row];
  if (c > CAP) c = CAP;
  if (c < 0) c = 0;
  float bs = FLT_MAX;
  int bk = 0;
  for (int j = 0; j < c; ++j) {
    const int k = cands[(size_t)row * CAP + j];
    if ((unsigned)k >= (unsigned)K_CODES) continue;   // defensive, never fires
    const float* er = e + (size_t)k * DIM;
    float dot = 0.f;
#pragma unroll
    for (int d = 0; d < DIM; ++d) dot = fmaf(zr[d], er[d], dot);
    const float s = fmaf(-2.f, dot, zq);   // bit-exact vs reference (round 2)
    if (s < bs || (s == bs && k < bk)) { bs = s; bk = k; }
  }
  oidx[row] = bk;
  oidxf[row] = (float)bk;
}

// -------------------------------------------------------- gather + loss ----
__global__ __launch_bounds__(256) void vq_gather_loss(
    const float* __restrict__ z, const float* __restrict__ e,
    const int* __restrict__ idx, float* __restrict__ qout,
    float* __restrict__ partials) {
  const int tid = threadIdx.x;
  const int rl = tid >> 4;
  const int t = tid & 15;
  const int row = blockIdx.x * 16 + rl;
  const int id = idx[row];
  const float4 qv =
      *reinterpret_cast<const float4*>(e + (size_t)id * DIM + 4 * t);
  const float4 zv =
      *reinterpret_cast<const float4*>(z + (size_t)row * DIM + 4 * t);
  *reinterpret_cast<float4*>(qout + (size_t)row * DIM + 4 * t) = qv;
  const float dx = zv.x - qv.x, dy = zv.y - qv.y;
  const float dz = zv.z - qv.z, dw = zv.w - qv.w;
  float s = dx * dx + dy * dy + dz * dz + dw * dw;

  __shared__ float red[256];
  red[tid] = s;
  __syncthreads();
  for (int off = 128; off > 0; off >>= 1) {
    if (tid < off) red[tid] += red[tid + off];
    __syncthreads();
  }
  if (tid == 0) partials[blockIdx.x] = red[0];
}

// ------------------------------------------------------------ finalize ----
__global__ __launch_bounds__(256) void vq_finalize(
    const float* __restrict__ partials, float* __restrict__ loss_out) {
  const int tid = threadIdx.x;
  float s = 0.f;
#pragma unroll
  for (int j = 0; j < 8; ++j) s += partials[tid + 256 * j];
  __shared__ float red[256];
  red[tid] = s;
  __syncthreads();
  for (int off = 128; off > 0; off >>= 1) {
    if (tid < off) red[tid] += red[tid + off];
    __syncthreads();
  }
  if (tid == 0) {
    const float loss = red[0] / (float)(N_ROWS * DIM);
    loss_out[0] = loss;
    loss_out[1] = loss;
  }
}

extern "C" void kernel_launch(void* const* d_in, const int* in_sizes, int n_in,
                              void* d_out, int out_size, void* d_ws,
                              size_t ws_size, hipStream_t stream) {
  const float* z = (const float*)d_in[0];   // [32768, 64]
  const float* e = (const float*)d_in[1];   // [8192, 64]
  float* out = (float*)d_out;
  float* qout = out;
  float* loss_out = out + (size_t)N_ROWS * DIM;
  float* idxf_out = loss_out + 2;

  char* ws = (char*)d_ws;
  float* partials = (float*)(ws + WS_PARTIALS);
  float* zsq = (float*)(ws + WS_ZSQ);
  int* idx = (int*)(ws + WS_IDX);
  unsigned short* ebf = (unsigned short*)(ws + WS_EBF);
  unsigned short* zbf = (unsigned short*)(ws + WS_ZBF);
  float* wsmax = (float*)(ws + WS_MAX);
  float* thr = (float*)(ws + WS_THR);
  int* cnt = (int*)(ws + WS_CNT);
  int* cands = (int*)(ws + WS_CANDS);   // overlays wsmax (dead after vq_thr)

  hipMemsetAsync(cnt, 0, N_ROWS * sizeof(int), stream);
  vq_zsq<<<N_ROWS / 256, 256, 0, stream>>>(z, zsq);
  vq_cvt_frag<<<(K_CODES * DIM / 8) / 256, 256, 0, stream>>>(e, ebf);
  vq_cvt_frag<<<(N_ROWS * DIM / 8) / 256, 256, 0, stream>>>(z, zbf);
  vq_sweep_max<<<64 * KSPLIT, 256, 0, stream>>>(zbf, ebf, wsmax);
  vq_thr<<<N_ROWS / 256, 256, 0, stream>>>(wsmax, thr);
  vq_sweep_collect<<<64 * KSPLIT, 256, 0, stream>>>(zbf, ebf, thr, cnt, cands);
  vq_resolve<<<N_ROWS / 256, 256, 0, stream>>>(z, e, zsq, cnt, cands, idx,
                                               idxf_out);
  vq_gather_loss<<<N_ROWS / 16, 256, 0, stream>>>(z, e, idx, qout, partials);
  vq_finalize<<<1, 256, 0, stream>>>(partials, loss_out);
}

// Round 14
// 147.274 us; speedup vs baseline: 1.8687x; 1.0062x over previous
//
#include <hip/hip_runtime.h>
#include <float.h>

#define N_ROWS  32768
#define K_CODES 8192
#define DIM     64
#define KSPLIT  32
#define KPART   (K_CODES / KSPLIT)   // 256 codes per slab
#define TILEK   64                   // codes per LDS tile (8 KB)
#define NTILES  (KPART / TILEK)      // 4
#define TSTEPS  (TILEK / 16)         // 4 fragment-steps per tile
#define CAP     32
#define DELTA_D 2e-4f

typedef __attribute__((ext_vector_type(8))) short bf16x8;
typedef __attribute__((ext_vector_type(4))) float f32x4;

// ws layout (bytes) — EXACT r6/r13-proven map (total 9969664):
#define WS_PARTIALS 0          // 2048 f    (8 KB)   -> 8192
#define WS_ZSQ      8192       // 32768 f   (128 KB) -> 139264
#define WS_IDX      139264     // 32768 i   (128 KB) -> 270336
#define WS_ACT      139264     // u8[32][2048] (64 KB) — overlays IDX: written by
                               // vq_thr, read by collect, then resolve overwrites
                               // the region with idx (strictly later in stream)
#define WS_EBF      270336     // 8192*64 bf16 frag (1 MB) -> 1318912
#define WS_ZBF      1318912    // 32768*64 bf16 frag (4 MB) -> 5513216
#define WS_MAX      5513216    // [32][32768] f (4 MB) -> 9707520
#define WS_CANDS    5513216    // 32768*32 i (4 MB) — overlays WS_MAX (dead after thr)
#define WS_THR      9707520    // 32768 f (128 KB) -> 9838592
#define WS_CNT      9838592    // 32768 i (128 KB) -> 9969664 total

__device__ __forceinline__ unsigned short f2bf(float f) {
  unsigned u = __float_as_uint(f);
  u = (u + 0x7fffu + ((u >> 16) & 1u)) >> 16;   // RNE, finite inputs
  return (unsigned short)u;
}

__device__ __forceinline__ void gload_lds16(const void* g, void* l) {
  typedef const __attribute__((address_space(1))) unsigned int* gp_t;
  typedef __attribute__((address_space(3))) unsigned int* lp_t;
  __builtin_amdgcn_global_load_lds((gp_t)g, (lp_t)l, 16, 0, 0);
}

#define MFMA16(a, b, c) __builtin_amdgcn_mfma_f32_16x16x32_bf16((a), (b), (c), 0, 0, 0)

// ----------------------------------------------------------------- z_sq ----
// Bit-exact numpy pairwise sum of z*z over 64 elems (validated round 2).
__global__ __launch_bounds__(256) void vq_zsq(const float* __restrict__ z,
                                              float* __restrict__ zsq) {
  const int row = blockIdx.x * 256 + threadIdx.x;
  const float4* z4 = reinterpret_cast<const float4*>(z + (size_t)row * DIM);
  float r[8];
  {
    const float4 v0 = z4[0], v1 = z4[1];
    r[0] = __fmul_rn(v0.x, v0.x); r[1] = __fmul_rn(v0.y, v0.y);
    r[2] = __fmul_rn(v0.z, v0.z); r[3] = __fmul_rn(v0.w, v0.w);
    r[4] = __fmul_rn(v1.x, v1.x); r[5] = __fmul_rn(v1.y, v1.y);
    r[6] = __fmul_rn(v1.z, v1.z); r[7] = __fmul_rn(v1.w, v1.w);
  }
#pragma unroll
  for (int i = 1; i < 8; ++i) {
    const float4 v0 = z4[2 * i], v1 = z4[2 * i + 1];
    r[0] = __fadd_rn(r[0], __fmul_rn(v0.x, v0.x));
    r[1] = __fadd_rn(r[1], __fmul_rn(v0.y, v0.y));
    r[2] = __fadd_rn(r[2], __fmul_rn(v0.z, v0.z));
    r[3] = __fadd_rn(r[3], __fmul_rn(v0.w, v0.w));
    r[4] = __fadd_rn(r[4], __fmul_rn(v1.x, v1.x));
    r[5] = __fadd_rn(r[5], __fmul_rn(v1.y, v1.y));
    r[6] = __fadd_rn(r[6], __fmul_rn(v1.z, v1.z));
    r[7] = __fadd_rn(r[7], __fmul_rn(v1.w, v1.w));
  }
  zsq[row] = __fadd_rn(
      __fadd_rn(__fadd_rn(r[0], r[1]), __fadd_rn(r[2], r[3])),
      __fadd_rn(__fadd_rn(r[4], r[5]), __fadd_rn(r[6], r[7])));
}

// ------------------------------------------------- cvt to fragment order ----
// chunk c (8 bf16 = 16B): l=c&63, h=(c>>6)&1, t=c>>7
//   dst[c] = src[idx = t*16 + (l&15)][d = h*32 + (l>>4)*8 .. +8]
__global__ __launch_bounds__(256) void vq_cvt_frag(
    const float* __restrict__ src, unsigned short* __restrict__ dst) {
  const int c = blockIdx.x * 256 + threadIdx.x;
  const int l = c & 63, h = (c >> 6) & 1, t = c >> 7;
  const float* p =
      src + (size_t)(t * 16 + (l & 15)) * DIM + h * 32 + ((l >> 4) << 3);
  const float4 f0 = *reinterpret_cast<const float4*>(p);
  const float4 f1 = *reinterpret_cast<const float4*>(p + 4);
  ushort4 o0, o1;
  o0.x = f2bf(f0.x); o0.y = f2bf(f0.y); o0.z = f2bf(f0.z); o0.w = f2bf(f0.w);
  o1.x = f2bf(f1.x); o1.y = f2bf(f1.y); o1.z = f2bf(f1.z); o1.w = f2bf(f1.w);
  reinterpret_cast<ushort4*>(dst)[2 * c] = o0;
  reinterpret_cast<ushort4*>(dst)[2 * c + 1] = o1;
}

// --------------------------------------------- pass A: per-row max(dot~) ----
// r13 structure, groups merged: 8 row-tiles per wave in one pass (bz[8][2] is
// spill-free per collect's proven register profile), whole 256-code slab in
// 32 KB LDS staged once. 16 steps x (2 ds_read_b128 + 16 MFMA).
__global__ __launch_bounds__(256) void vq_sweep_max(
    const unsigned short* __restrict__ zbf,
    const unsigned short* __restrict__ ebf, float* __restrict__ wsmax) {
  __shared__ char lds[KPART * DIM * 2];   // 32 KB
  const int tid = threadIdx.x;
  const int wid = tid >> 6, l = tid & 63;
  const int rowblk = blockIdx.x & 63, kp = blockIdx.x >> 6;
  const int waveRow = rowblk * 512 + wid * 128;
  const int baseTile = waveRow >> 4;

  const char* slab = (const char*)ebf + (size_t)kp * (KPART * DIM * 2);
#pragma unroll
  for (int c = 0; c < 8; ++c)
    gload_lds16(slab + (c * 256 + tid) * 16, lds + (c * 256 + tid) * 16);
  __syncthreads();

  const f32x4 zero = {0.f, 0.f, 0.f, 0.f};

  bf16x8 bz[8][2];
#pragma unroll
  for (int rt = 0; rt < 8; ++rt)
#pragma unroll
    for (int h = 0; h < 2; ++h)
      bz[rt][h] = *reinterpret_cast<const bf16x8*>(
          zbf + ((size_t)((baseTile + rt) * 2 + h) * 64 + l) * 8);

  float m[8];
#pragma unroll
  for (int rt = 0; rt < 8; ++rt) m[rt] = -FLT_MAX;

#pragma unroll 2
  for (int s = 0; s < KPART / 16; ++s) {   // 16 steps
    const bf16x8 a0 = *reinterpret_cast<const bf16x8*>(lds + s * 2048 + l * 16);
    const bf16x8 a1 =
        *reinterpret_cast<const bf16x8*>(lds + s * 2048 + 1024 + l * 16);
#pragma unroll
    for (int rt = 0; rt < 8; ++rt) {
      f32x4 t = MFMA16(a0, bz[rt][0], zero);
      t = MFMA16(a1, bz[rt][1], t);
      m[rt] = fmaxf(m[rt], fmaxf(fmaxf(t[0], t[1]), fmaxf(t[2], t[3])));
    }
  }

#pragma unroll
  for (int rt = 0; rt < 8; ++rt) {
    float mm = m[rt];
    mm = fmaxf(mm, __shfl_xor(mm, 16, 64));
    mm = fmaxf(mm, __shfl_xor(mm, 32, 64));
    if (l < 16)
      wsmax[(size_t)kp * N_ROWS + waveRow + rt * 16 + l] = mm;
  }
}

// ------------- thr + per-(slab, 16-row-tile) activity flags (for skip) ----
// act[kp][tile] = 1 iff any row in tile has wsmax[kp][row] >= thr[row].
// A code in slab kp can only be a candidate for row if wsmax[kp][row] >=
// thr[row] (slab max bounds every member), so skipping inactive tiles in
// collect preserves the candidate set EXACTLY.
__global__ __launch_bounds__(256) void vq_thr(const float* __restrict__ wsmax,
                                              float* __restrict__ thr,
                                              unsigned char* __restrict__ act) {
  const int row = blockIdx.x * 256 + threadIdx.x;
  const int l = threadIdx.x & 63;
  float m = -FLT_MAX;
#pragma unroll
  for (int p = 0; p < KSPLIT; ++p)
    m = fmaxf(m, wsmax[(size_t)p * N_ROWS + row]);
  const float t = m - DELTA_D;
  thr[row] = t;
#pragma unroll
  for (int p = 0; p < KSPLIT; ++p) {
    const bool a = wsmax[(size_t)p * N_ROWS + row] >= t;
    const unsigned long long bal = __ballot(a);
    if ((l & 15) == 0) {   // one writer per 16-row tile
      const unsigned nib = (unsigned)((bal >> (l & 48)) & 0xFFFFull);
      act[p * (N_ROWS / 16) + (row >> 4)] = nib ? 1 : 0;
    }
  }
}

// ----------------------------------- pass B: collect near-max candidates ----
// r13-proven dbuf structure + wave-uniform tile-skip: per rt, the MFMA+check
// runs only if act says the (slab, tile) pair can contain candidates
// (~42% of tiles). Skip branch is wave-uniform (s_cbranch, no divergence).
__global__ __launch_bounds__(256, 4) void vq_sweep_collect(
    const unsigned short* __restrict__ zbf,
    const unsigned short* __restrict__ ebf, const float* __restrict__ thrbuf,
    const unsigned char* __restrict__ act, int* __restrict__ cnt,
    int* __restrict__ cands) {
  __shared__ f32x4 lds4[1024];
  char* lds = (char*)lds4;
  const int tid = threadIdx.x;
  const int wid = tid >> 6, l = tid & 63;
  const int l15 = l & 15, lg = l >> 4;
  const int rowblk = blockIdx.x & 63, kp = blockIdx.x >> 6;
  const int kb = kp * KPART;
  const int waveRow = rowblk * 512 + wid * 128;
  const int baseTile = waveRow >> 4;

  // 8 activity flags for this wave's tiles, one uniform 8-byte load
  const unsigned long long act8 = *reinterpret_cast<const unsigned long long*>(
      act + (size_t)kp * (N_ROWS / 16) + baseTile);

  bf16x8 bz[8][2];
#pragma unroll
  for (int rt = 0; rt < 8; ++rt)
#pragma unroll
    for (int h = 0; h < 2; ++h)
      bz[rt][h] = *reinterpret_cast<const bf16x8*>(
          zbf + ((size_t)((baseTile + rt) * 2 + h) * 64 + l) * 8);

  float thr[8];
#pragma unroll
  for (int rt = 0; rt < 8; ++rt)
    thr[rt] = thrbuf[waveRow + rt * 16 + l15];

  const char* slab = (const char*)ebf + (size_t)kp * (KPART * DIM * 2);
#pragma unroll
  for (int c = 0; c < 2; ++c)
    gload_lds16(slab + (wid * 2 + c) * 1024 + l * 16,
                lds + (wid * 2 + c) * 1024);
  __syncthreads();

  const f32x4 zero = {0.f, 0.f, 0.f, 0.f};

  for (int tk = 0; tk < NTILES; ++tk) {
    char* cur = lds + (tk & 1) * 8192;
    if (tk + 1 < NTILES) {
      char* nxt = lds + ((tk + 1) & 1) * 8192;
      const char* src = slab + (size_t)(tk + 1) * 8192;
#pragma unroll
      for (int c = 0; c < 2; ++c)
        gload_lds16(src + (wid * 2 + c) * 1024 + l * 16,
                    nxt + (wid * 2 + c) * 1024);
    }
#pragma unroll
    for (int s = 0; s < TSTEPS; ++s) {
      const bf16x8 a0 = *reinterpret_cast<const bf16x8*>(cur + s * 2048 + l * 16);
      const bf16x8 a1 =
          *reinterpret_cast<const bf16x8*>(cur + s * 2048 + 1024 + l * 16);
#pragma unroll
      for (int rt = 0; rt < 8; ++rt) {
        if ((act8 >> (8 * rt)) & 0xFF) {   // wave-uniform tile skip
          f32x4 t = MFMA16(a0, bz[rt][0], zero);
          t = MFMA16(a1, bz[rt][1], t);    // bit-identical to pass A
          if (t[0] >= thr[rt] || t[1] >= thr[rt] || t[2] >= thr[rt] ||
              t[3] >= thr[rt]) {           // rare
            const int row = waveRow + rt * 16 + l15;
            const int kbase = kb + tk * TILEK + s * 16 + lg * 4;
#pragma unroll
            for (int i = 0; i < 4; ++i)
              if (t[i] >= thr[rt]) {
                const int pos = atomicAdd(&cnt[row], 1);
                if (pos < CAP) cands[(size_t)row * CAP + pos] = kbase + i;
              }
          }
        }
      }
    }
    __syncthreads();
  }
}

// ------------------------- resolve: exact ref chain on candidates only ----
// r4/r13-proven thread-per-row version (+ harmless k range guard).
__global__ __launch_bounds__(256) void vq_resolve(
    const float* __restrict__ z, const float* __restrict__ e,
    const float* __restrict__ zsq, const int* __restrict__ cnt,
    const int* __restrict__ cands, int* __restrict__ oidx,
    float* __restrict__ oidxf) {
  const int row = blockIdx.x * 256 + threadIdx.x;
  float zr[DIM];
#pragma unroll
  for (int t = 0; t < DIM / 4; ++t) {
    const float4 v = reinterpret_cast<const float4*>(z + (size_t)row * DIM)[t];
    zr[4 * t + 0] = v.x; zr[4 * t + 1] = v.y;
    zr[4 * t + 2] = v.z; zr[4 * t + 3] = v.w;
  }
  const float zq = zsq[row];
  int c = cnt[row];
  if (c > CAP) c = CAP;
  if (c < 0) c = 0;
  float bs = FLT_MAX;
  int bk = 0;
  for (int j = 0; j < c; ++j) {
    const int k = cands[(size_t)row * CAP + j];
    if ((unsigned)k >= (unsigned)K_CODES) continue;   // defensive, never fires
    const float* er = e + (size_t)k * DIM;
    float dot = 0.f;
#pragma unroll
    for (int d = 0; d < DIM; ++d) dot = fmaf(zr[d], er[d], dot);
    const float s = fmaf(-2.f, dot, zq);   // bit-exact vs reference (round 2)
    if (s < bs || (s == bs && k < bk)) { bs = s; bk = k; }
  }
  oidx[row] = bk;
  oidxf[row] = (float)bk;
}

// -------------------------------------------------------- gather + loss ----
__global__ __launch_bounds__(256) void vq_gather_loss(
    const float* __restrict__ z, const float* __restrict__ e,
    const int* __restrict__ idx, float* __restrict__ qout,
    float* __restrict__ partials) {
  const int tid = threadIdx.x;
  const int rl = tid >> 4;
  const int t = tid & 15;
  const int row = blockIdx.x * 16 + rl;
  const int id = idx[row];
  const float4 qv =
      *reinterpret_cast<const float4*>(e + (size_t)id * DIM + 4 * t);
  const float4 zv =
      *reinterpret_cast<const float4*>(z + (size_t)row * DIM + 4 * t);
  *reinterpret_cast<float4*>(qout + (size_t)row * DIM + 4 * t) = qv;
  const float dx = zv.x - qv.x, dy = zv.y - qv.y;
  const float dz = zv.z - qv.z, dw = zv.w - qv.w;
  float s = dx * dx + dy * dy + dz * dz + dw * dw;

  __shared__ float red[256];
  red[tid] = s;
  __syncthreads();
  for (int off = 128; off > 0; off >>= 1) {
    if (tid < off) red[tid] += red[tid + off];
    __syncthreads();
  }
  if (tid == 0) partials[blockIdx.x] = red[0];
}

// ------------------------------------------------------------ finalize ----
__global__ __launch_bounds__(256) void vq_finalize(
    const float* __restrict__ partials, float* __restrict__ loss_out) {
  const int tid = threadIdx.x;
  float s = 0.f;
#pragma unroll
  for (int j = 0; j < 8; ++j) s += partials[tid + 256 * j];
  __shared__ float red[256];
  red[tid] = s;
  __syncthreads();
  for (int off = 128; off > 0; off >>= 1) {
    if (tid < off) red[tid] += red[tid + off];
    __syncthreads();
  }
  if (tid == 0) {
    const float loss = red[0] / (float)(N_ROWS * DIM);
    loss_out[0] = loss;
    loss_out[1] = loss;
  }
}

extern "C" void kernel_launch(void* const* d_in, const int* in_sizes, int n_in,
                              void* d_out, int out_size, void* d_ws,
                              size_t ws_size, hipStream_t stream) {
  const float* z = (const float*)d_in[0];   // [32768, 64]
  const float* e = (const float*)d_in[1];   // [8192, 64]
  float* out = (float*)d_out;
  float* qout = out;
  float* loss_out = out + (size_t)N_ROWS * DIM;
  float* idxf_out = loss_out + 2;

  char* ws = (char*)d_ws;
  float* partials = (float*)(ws + WS_PARTIALS);
  float* zsq = (float*)(ws + WS_ZSQ);
  int* idx = (int*)(ws + WS_IDX);
  unsigned char* act = (unsigned char*)(ws + WS_ACT);   // overlays idx (see map)
  unsigned short* ebf = (unsigned short*)(ws + WS_EBF);
  unsigned short* zbf = (unsigned short*)(ws + WS_ZBF);
  float* wsmax = (float*)(ws + WS_MAX);
  float* thr = (float*)(ws + WS_THR);
  int* cnt = (int*)(ws + WS_CNT);
  int* cands = (int*)(ws + WS_CANDS);   // overlays wsmax (dead after vq_thr)

  hipMemsetAsync(cnt, 0, N_ROWS * sizeof(int), stream);
  vq_zsq<<<N_ROWS / 256, 256, 0, stream>>>(z, zsq);
  vq_cvt_frag<<<(K_CODES * DIM / 8) / 256, 256, 0, stream>>>(e, ebf);
  vq_cvt_frag<<<(N_ROWS * DIM / 8) / 256, 256, 0, stream>>>(z, zbf);
  vq_sweep_max<<<64 * KSPLIT, 256, 0, stream>>>(zbf, ebf, wsmax);
  vq_thr<<<N_ROWS / 256, 256, 0, stream>>>(wsmax, thr, act);
  vq_sweep_collect<<<64 * KSPLIT, 256, 0, stream>>>(zbf, ebf, thr, act, cnt,
                                                    cands);
  vq_resolve<<<N_ROWS / 256, 256, 0, stream>>>(z, e, zsq, cnt, cands, idx,
                                               idxf_out);
  vq_gather_loss<<<N_ROWS / 16, 256, 0, stream>>>(z, e, idx, qout, partials);
  vq_finalize<<<1, 256, 0, stream>>>(partials, loss_out);
}